// Round 1
// baseline (214.861 us; speedup 1.0000x reference)
//
#include <hip/hip_runtime.h>
#include <cstdint>

typedef unsigned short u16;
typedef __attribute__((ext_vector_type(4))) float f32x4;
typedef __attribute__((ext_vector_type(8))) short bf16x8;
typedef __attribute__((ext_vector_type(4))) u16 u16x4;

#define B_C 2
#define T_C 2048
#define H_C 16
#define KV_C 4
#define NQKV_C 1536

__device__ __forceinline__ u16 f2bf(float f) {
  unsigned u = __builtin_bit_cast(unsigned, f);
  u = (u + 0x7fffu + ((u >> 16) & 1u)) >> 16;
  return (u16)u;
}

// ---------- x: fp32 -> bf16 ----------
__global__ void k_cvt(const float* __restrict__ in, u16* __restrict__ out, int n4) {
  int i = blockIdx.x * blockDim.x + threadIdx.x;
  if (i >= n4) return;
  f32x4 v = *(const f32x4*)(in + (size_t)i * 4);
  u16x4 o;
  o[0] = f2bf(v[0]); o[1] = f2bf(v[1]); o[2] = f2bf(v[2]); o[3] = f2bf(v[3]);
  *(u16x4*)(out + (size_t)i * 4) = o;
}

// ---------- transpose fp32 [K][N] -> bf16 [N][K] ----------
__global__ void k_tr(const float* __restrict__ in, u16* __restrict__ out, int K, int N) {
  __shared__ float t[32][33];
  int kb = blockIdx.x * 32, nb = blockIdx.y * 32;
  int tx = threadIdx.x & 31, ty = threadIdx.x >> 5;
#pragma unroll
  for (int i = 0; i < 32; i += 8) t[ty + i][tx] = in[(size_t)(kb + ty + i) * N + nb + tx];
  __syncthreads();
#pragma unroll
  for (int i = 0; i < 32; i += 8) out[(size_t)(nb + ty + i) * K + kb + tx] = f2bf(t[tx][ty + i]);
}

// ---------- GEMM: C[M][N] fp32 = A[M][K]bf16 * Bt[N][K]bf16^T ----------
__global__ __launch_bounds__(256, 2) void k_gemm_bt(
    const u16* __restrict__ A, const u16* __restrict__ Bt, float* __restrict__ C,
    int M, int N, int K) {
  constexpr int BK = 32;
  __shared__ u16 As[128 * BK];
  __shared__ u16 Bs[128 * BK];
  const int tid = threadIdx.x;
  const int lane = tid & 63, wid = tid >> 6;
  const int wr = wid >> 1, wc = wid & 1;
  const int l15 = lane & 15, lhi = lane >> 4;
  const int bm = blockIdx.x * 128, bn = blockIdx.y * 128;
  const int srow = tid >> 2, scol = (tid & 3) * 8;
  const u16* ga = A + (size_t)(bm + srow) * K + scol;
  const u16* gb = Bt + (size_t)(bn + srow) * K + scol;
  f32x4 acc[4][4] = {};
  const int aoff = (wr * 64 + l15) * BK + lhi * 8;
  const int boff = (wc * 64 + l15) * BK + lhi * 8;
  for (int k0 = 0; k0 < K; k0 += BK) {
    __syncthreads();
    __builtin_amdgcn_global_load_lds((__attribute__((address_space(1))) void*)(ga + k0),
                                     (__attribute__((address_space(3))) void*)(&As[tid * 8]), 16, 0, 0);
    __builtin_amdgcn_global_load_lds((__attribute__((address_space(1))) void*)(ga + (size_t)64 * K + k0),
                                     (__attribute__((address_space(3))) void*)(&As[2048 + tid * 8]), 16, 0, 0);
    __builtin_amdgcn_global_load_lds((__attribute__((address_space(1))) void*)(gb + k0),
                                     (__attribute__((address_space(3))) void*)(&Bs[tid * 8]), 16, 0, 0);
    __builtin_amdgcn_global_load_lds((__attribute__((address_space(1))) void*)(gb + (size_t)64 * K + k0),
                                     (__attribute__((address_space(3))) void*)(&Bs[2048 + tid * 8]), 16, 0, 0);
    __syncthreads();
    bf16x8 af[4], bfr[4];
#pragma unroll
    for (int i = 0; i < 4; i++) af[i] = *(const bf16x8*)&As[aoff + i * 16 * BK];
#pragma unroll
    for (int j = 0; j < 4; j++) bfr[j] = *(const bf16x8*)&Bs[boff + j * 16 * BK];
#pragma unroll
    for (int i = 0; i < 4; i++)
#pragma unroll
      for (int j = 0; j < 4; j++)
        acc[i][j] = __builtin_amdgcn_mfma_f32_16x16x32_bf16(af[i], bfr[j], acc[i][j], 0, 0, 0);
  }
  const int crow0 = bm + wr * 64 + lhi * 4, ccol0 = bn + wc * 64 + l15;
#pragma unroll
  for (int i = 0; i < 4; i++)
#pragma unroll
    for (int j = 0; j < 4; j++)
#pragma unroll
      for (int r = 0; r < 4; r++)
        C[(size_t)(crow0 + i * 16 + r) * N + ccol0 + j * 16] = acc[i][j][r];
}

// ---------- RoPE + relayout ----------
__global__ void k_rope(const float* __restrict__ qkv, u16* __restrict__ qb,
                       u16* __restrict__ kb, u16* __restrict__ vb) {
  const int QP = B_C * H_C * T_C * 32;   // 2097152
  const int KP = B_C * KV_C * T_C * 32;  // 524288
  const int VN = B_C * KV_C * T_C * 64;  // 1048576
  int idx = blockIdx.x * blockDim.x + threadIdx.x;
  const float L2T = 13.28771237954945f;  // log2(10000)
  if (idx < QP) {
    int i = idx & 31, t = (idx >> 5) & 2047, h = (idx >> 16) & 15, b = idx >> 20;
    const float* src = qkv + (size_t)(b * T_C + t) * NQKV_C + h * 64 + 2 * i;
    float e = src[0], o = src[1];
    float ang = (float)t * exp2f(-(float)(2 * i) * (L2T / 64.0f));
    float sn, cs; sincosf(ang, &sn, &cs);
    size_t ob = ((size_t)((b * H_C + h) * T_C + t)) * 64 + 2 * i;
    qb[ob]     = f2bf((e * cs - o * sn) * 0.125f);
    qb[ob + 1] = f2bf((e * sn + o * cs) * 0.125f);
  } else if (idx < QP + KP) {
    int j = idx - QP;
    int i = j & 31, t = (j >> 5) & 2047, g = (j >> 16) & 3, b = j >> 18;
    const float* src = qkv + (size_t)(b * T_C + t) * NQKV_C + 1024 + g * 64 + 2 * i;
    float e = src[0], o = src[1];
    float ang = (float)t * exp2f(-(float)(2 * i) * (L2T / 64.0f));
    float sn, cs; sincosf(ang, &sn, &cs);
    size_t ob = ((size_t)((b * KV_C + g) * T_C + t)) * 64 + 2 * i;
    kb[ob]     = f2bf(e * cs - o * sn);
    kb[ob + 1] = f2bf(e * sn + o * cs);
  } else {
    int j = idx - QP - KP;
    if (j >= VN) return;
    int d = j & 63, t = (j >> 6) & 2047, g = (j >> 17) & 3, b = j >> 19;
    vb[((size_t)((b * KV_C + g) * T_C + t)) * 64 + d] =
        f2bf(qkv[(size_t)(b * T_C + t) * NQKV_C + 1280 + g * 64 + d]);
  }
}

// ---------- causal flash attention (bf16 MFMA, fp32 online softmax) ----------
__global__ __launch_bounds__(256, 4) void k_attn(
    const u16* __restrict__ q_bf, const u16* __restrict__ k_bf,
    const u16* __restrict__ v_bf, u16* __restrict__ att_bf) {
  __shared__ u16 Ks[64][72];
  __shared__ u16 Vt[64][72];
  __shared__ u16 Ps[4][16][72];
  const int qb = blockIdx.x, h = blockIdx.y, b = blockIdx.z;
  const int kvh = h >> 2;
  const int tid = threadIdx.x, lane = tid & 63, w = tid >> 6;
  const int l15 = lane & 15, lhi = lane >> 4;
  const u16* Qg = q_bf + ((size_t)((b * H_C + h) * T_C) + qb * 64) * 64;
  const u16* Kg = k_bf + ((size_t)((b * KV_C + kvh) * T_C)) * 64;
  const u16* Vg = v_bf + ((size_t)((b * KV_C + kvh) * T_C)) * 64;

  bf16x8 qf[2];
  const int qrow = w * 16 + l15;
#pragma unroll
  for (int c = 0; c < 2; c++) qf[c] = *(const bf16x8*)&Qg[qrow * 64 + c * 32 + lhi * 8];

  f32x4 o[4] = {};
  float m[4], lsum[4];
#pragma unroll
  for (int r = 0; r < 4; r++) { m[r] = -1e30f; lsum[r] = 0.f; }

  const int nt = qb + 1;
  const int strow = tid >> 2, stcol = (tid & 3) * 16;
  for (int it = 0; it < nt; ++it) {
    const int t0 = it * 64;
    __syncthreads();
    {  // stage K rows and V^T
      bf16x8 kv0 = *(const bf16x8*)&Kg[(size_t)(t0 + strow) * 64 + stcol];
      bf16x8 kv1 = *(const bf16x8*)&Kg[(size_t)(t0 + strow) * 64 + stcol + 8];
      *(bf16x8*)&Ks[strow][stcol] = kv0;
      *(bf16x8*)&Ks[strow][stcol + 8] = kv1;
      bf16x8 vv0 = *(const bf16x8*)&Vg[(size_t)(t0 + strow) * 64 + stcol];
      bf16x8 vv1 = *(const bf16x8*)&Vg[(size_t)(t0 + strow) * 64 + stcol + 8];
#pragma unroll
      for (int j = 0; j < 8; j++) Vt[stcol + j][strow] = (u16)vv0[j];
#pragma unroll
      for (int j = 0; j < 8; j++) Vt[stcol + 8 + j][strow] = (u16)vv1[j];
    }
    __syncthreads();
    // S = Q K^T
    f32x4 s[4] = {};
#pragma unroll
    for (int nf = 0; nf < 4; nf++)
#pragma unroll
      for (int kc = 0; kc < 2; kc++) {
        bf16x8 kf = *(const bf16x8*)&Ks[nf * 16 + l15][kc * 32 + lhi * 8];
        s[nf] = __builtin_amdgcn_mfma_f32_16x16x32_bf16(qf[kc], kf, s[nf], 0, 0, 0);
      }
    // causal mask on diagonal tile
    if (it == nt - 1) {
      const int qg = qb * 64 + w * 16 + lhi * 4;
#pragma unroll
      for (int nf = 0; nf < 4; nf++) {
        const int key = t0 + nf * 16 + l15;
#pragma unroll
        for (int r = 0; r < 4; r++)
          if (key > qg + r) s[nf][r] = -1e30f;
      }
    }
    // online softmax (rows live in 16-lane groups)
    float tmax[4];
#pragma unroll
    for (int r = 0; r < 4; r++)
      tmax[r] = fmaxf(fmaxf(s[0][r], s[1][r]), fmaxf(s[2][r], s[3][r]));
#pragma unroll
    for (int x = 1; x < 16; x <<= 1)
#pragma unroll
      for (int r = 0; r < 4; r++) tmax[r] = fmaxf(tmax[r], __shfl_xor(tmax[r], x, 64));
    float alpha[4];
#pragma unroll
    for (int r = 0; r < 4; r++) {
      float mn = fmaxf(m[r], tmax[r]);
      alpha[r] = __expf(m[r] - mn);
      m[r] = mn;
    }
    float psum[4] = {0.f, 0.f, 0.f, 0.f};
#pragma unroll
    for (int nf = 0; nf < 4; nf++)
#pragma unroll
      for (int r = 0; r < 4; r++) {
        float p = __expf(s[nf][r] - m[r]);
        s[nf][r] = p;
        psum[r] += p;
      }
#pragma unroll
    for (int x = 1; x < 16; x <<= 1)
#pragma unroll
      for (int r = 0; r < 4; r++) psum[r] += __shfl_xor(psum[r], x, 64);
#pragma unroll
    for (int r = 0; r < 4; r++) lsum[r] = lsum[r] * alpha[r] + psum[r];
    // P -> LDS (per-wave region) as bf16
#pragma unroll
    for (int nf = 0; nf < 4; nf++)
#pragma unroll
      for (int r = 0; r < 4; r++)
        Ps[w][lhi * 4 + r][nf * 16 + l15] = f2bf(s[nf][r]);
    asm volatile("s_waitcnt lgkmcnt(0)" ::: "memory");
    __builtin_amdgcn_sched_barrier(0);
    // rescale O
#pragma unroll
    for (int nf = 0; nf < 4; nf++)
#pragma unroll
      for (int r = 0; r < 4; r++) o[nf][r] *= alpha[r];
    // O += P V
#pragma unroll
    for (int kc = 0; kc < 2; kc++) {
      bf16x8 pa = *(const bf16x8*)&Ps[w][l15][kc * 32 + lhi * 8];
#pragma unroll
      for (int nf = 0; nf < 4; nf++) {
        bf16x8 vf = *(const bf16x8*)&Vt[nf * 16 + l15][kc * 32 + lhi * 8];
        o[nf] = __builtin_amdgcn_mfma_f32_16x16x32_bf16(pa, vf, o[nf], 0, 0, 0);
      }
    }
  }
  // epilogue: O/l -> att_bf [B*T][1024]
  const int trow = qb * 64 + w * 16 + lhi * 4;
  const size_t obase = ((size_t)(b * T_C) + trow) * 1024 + h * 64;
#pragma unroll
  for (int nf = 0; nf < 4; nf++)
#pragma unroll
    for (int r = 0; r < 4; r++)
      att_bf[obase + (size_t)r * 1024 + nf * 16 + l15] = f2bf(o[nf][r] / lsum[r]);
}

extern "C" void kernel_launch(void* const* d_in, const int* in_sizes, int n_in,
                              void* d_out, int out_size, void* d_ws, size_t ws_size,
                              hipStream_t stream) {
  const float* x  = (const float*)d_in[0];
  // d_in[1] = mask (pure causal tril — implemented directly)
  const float* wq = (const float*)d_in[2];
  const float* wk = (const float*)d_in[3];
  const float* wv = (const float*)d_in[4];
  const float* wo = (const float*)d_in[5];
  float* out = (float*)d_out;

  char* ws = (char*)d_ws;
  u16*   xb    = (u16*)(ws);                          //  8 MiB: [4096][1024] bf16
  u16*   wqkvT = (u16*)(ws + (8ull  << 20));          //  3 MiB: [1536][1024] bf16
  u16*   woT   = (u16*)(ws + (11ull << 20));          //  2 MiB: [1024][1024] bf16
  float* qkv   = (float*)(ws + (13ull << 20));        // 24 MiB: [4096][1536] fp32
  u16*   q_bf  = (u16*)(ws + (37ull << 20));          //  8 MiB: [2][16][2048][64]
  u16*   k_bf  = (u16*)(ws + (45ull << 20));          //  2 MiB: [2][4][2048][64]
  u16*   v_bf  = (u16*)(ws + (47ull << 20));          //  2 MiB
  u16*   attb  = (u16*)(ws + (49ull << 20));          //  8 MiB: [4096][1024] bf16

  k_cvt<<<4096, 256, 0, stream>>>(x, xb, 4096 * 1024 / 4);
  k_tr<<<dim3(32, 32), 256, 0, stream>>>(wq, wqkvT, 1024, 1024);
  k_tr<<<dim3(32, 8),  256, 0, stream>>>(wk, wqkvT + 1024 * 1024, 1024, 256);
  k_tr<<<dim3(32, 8),  256, 0, stream>>>(wv, wqkvT + 1280 * 1024, 1024, 256);
  k_tr<<<dim3(32, 32), 256, 0, stream>>>(wo, woT, 1024, 1024);
  k_gemm_bt<<<dim3(32, 12), 256, 0, stream>>>(xb, wqkvT, qkv, 4096, 1536, 1024);
  k_rope<<<14336, 256, 0, stream>>>(qkv, q_bf, k_bf, v_bf);
  k_attn<<<dim3(32, 16, 2), 256, 0, stream>>>(q_bf, k_bf, v_bf, attb);
  k_gemm_bt<<<dim3(32, 8), 256, 0, stream>>>(attb, woT, out, 4096, 1024, 1024);
}